// Round 5
// baseline (171.413 us; speedup 1.0000x reference)
//
#include <hip/hip_runtime.h>
#include <math.h>

// Problem constants
#define B_ 4
#define S_ 1024
#define HID_ 1024
#define NH_ 16
#define HD_ 64
#define NTOK (B_ * S_)           // 4096

typedef __attribute__((ext_vector_type(4))) float f32x4;
typedef __attribute__((ext_vector_type(8))) short bf16x8;   // 8 bf16 = 4 VGPRs

__device__ __forceinline__ unsigned short f2bf(float f) {
    union { float f; unsigned int u; } v; v.f = f;
    unsigned int r = v.u + 0x7fffu + ((v.u >> 16) & 1u);   // RNE
    return (unsigned short)(r >> 16);
}
__device__ __forceinline__ float bf2f(unsigned short u) {
    return __uint_as_float((unsigned int)u << 16);
}

// async global->LDS, 16 B per lane. LDS dest = wave-uniform base + lane*16.
__device__ __forceinline__ void load_lds16(const void* g, void* l) {
    __builtin_amdgcn_global_load_lds(
        (const __attribute__((address_space(1))) unsigned int*)(uintptr_t)g,
        (__attribute__((address_space(3))) unsigned int*)(uintptr_t)l,
        16, 0, 0);
}

// ---------------------------------------------------------------------------
// Kernel 0: f32 -> bf16 convert for x, Wq, Wk, Wv
// ---------------------------------------------------------------------------
__global__ __launch_bounds__(256) void cvt_all(
    const float* __restrict__ x, const float* __restrict__ wq,
    const float* __restrict__ wk, const float* __restrict__ wv,
    unsigned short* __restrict__ xb, unsigned short* __restrict__ wqb,
    unsigned short* __restrict__ wkb, unsigned short* __restrict__ wvb)
{
    const int which = blockIdx.y;
    const float* src = which == 0 ? x : which == 1 ? wq : which == 2 ? wk : wv;
    unsigned short* dst = which == 0 ? xb : which == 1 ? wqb : which == 2 ? wkb : wvb;
    const int n4 = (which == 0) ? (NTOK * HID_ / 4) : (HID_ * HID_ / 4);
    int i = blockIdx.x * 256 + threadIdx.x;
    if (i < n4) {
        float4 f = ((const float4*)src)[i];
        ushort4 o = make_ushort4(f2bf(f.x), f2bf(f.y), f2bf(f.z), f2bf(f.w));
        ((ushort4*)dst)[i] = o;
    }
}

// ---------------------------------------------------------------------------
// Kernel 1: QKV projection, bf16 MFMA (m97 structure).
// Q,K: C[token][feat] with A=x, B=W -> written [B,NH,S,HD].
// V:   OPERANDS SWAPPED: C'=W.x^T=V^T with A=W, B=x -> D-layout col maps to
//      tokens, so the [B,NH,HD,S] write is lane-contiguous in s (coalesced).
// ---------------------------------------------------------------------------
__global__ __launch_bounds__(256) void qkv_gemm_mfma(
    const unsigned short* __restrict__ xb,
    const unsigned short* __restrict__ Wqb, const float* __restrict__ bq,
    const unsigned short* __restrict__ Wkb, const float* __restrict__ bk,
    const unsigned short* __restrict__ Wvb, const float* __restrict__ bv,
    unsigned short* __restrict__ qout, unsigned short* __restrict__ kout,
    unsigned short* __restrict__ vtout)
{
    const int which = blockIdx.z;
    const unsigned short* __restrict__ W = which == 0 ? Wqb : which == 1 ? Wkb : Wvb;
    const float* __restrict__ bias       = which == 0 ? bq  : which == 1 ? bk  : bv;

    __shared__ unsigned short As[128 * 32];   // 8 KB, unpadded (global_load_lds)
    __shared__ unsigned short Bs[128 * 32];

    const int t    = threadIdx.x;
    const int lane = t & 63;
    const int w    = t >> 6;
    const int wr   = w >> 1;
    const int wc   = w & 1;

    const int bm = blockIdx.x;   // token tiles (32)
    const int bn = blockIdx.y;   // feature tiles (8)

    // Operand roles: which==2 swaps A<->B (m side = feats, n side = tokens)
    const unsigned short* __restrict__ Arow = (which == 2) ? W  : xb;
    const unsigned short* __restrict__ Brow = (which == 2) ? xb : W;
    const int am0 = (which == 2) ? bn * 128 : bm * 128;
    const int bn0 = (which == 2) ? bm * 128 : bn * 128;

    const int srow = t >> 2;
    const int sk   = (t & 3) << 3;
    const unsigned short* gA = Arow + (size_t)(am0 + srow) * HID_ + sk;
    const unsigned short* gB = Brow + (size_t)(bn0 + srow) * HID_ + sk;

    const f32x4 zero = {0.f, 0.f, 0.f, 0.f};
    f32x4 acc[4][4];
    #pragma unroll
    for (int i = 0; i < 4; ++i)
        #pragma unroll
        for (int j = 0; j < 4; ++j) acc[i][j] = zero;

    const int lrow = lane & 15;
    const int lk   = (lane >> 4) << 3;

    for (int k0 = 0; k0 < HID_; k0 += 32) {
        __syncthreads();
        load_lds16(gA + k0,              (char*)As + t * 16);
        load_lds16(gA + 64 * HID_ + k0,  (char*)As + 4096 + t * 16);
        load_lds16(gB + k0,              (char*)Bs + t * 16);
        load_lds16(gB + 64 * HID_ + k0,  (char*)Bs + 4096 + t * 16);
        __syncthreads();

        bf16x8 af[4], bf[4];
        #pragma unroll
        for (int i = 0; i < 4; ++i)
            af[i] = *(const bf16x8*)&As[(wr * 64 + i * 16 + lrow) * 32 + lk];
        #pragma unroll
        for (int j = 0; j < 4; ++j)
            bf[j] = *(const bf16x8*)&Bs[(wc * 64 + j * 16 + lrow) * 32 + lk];
        #pragma unroll
        for (int i = 0; i < 4; ++i)
            #pragma unroll
            for (int j = 0; j < 4; ++j)
                acc[i][j] = __builtin_amdgcn_mfma_f32_16x16x32_bf16(
                    af[i], bf[j], acc[i][j], 0, 0, 0);
    }

    // Epilogue. D layout: col=lane&15 (n side), row=(lane>>4)*4+r (m side)
    const int col   = lane & 15;
    const int rbase = (lane >> 4) << 2;
    if (which == 2) {
        // m = feat, n = token. Consecutive lanes -> consecutive s. V^T write.
        #pragma unroll
        for (int i = 0; i < 4; ++i) {
            #pragma unroll
            for (int r = 0; r < 4; ++r) {
                const int feat = bn * 128 + wr * 64 + i * 16 + rbase + r;
                const int h = feat >> 6, d = feat & 63;
                const float bias_v = bias[feat];
                #pragma unroll
                for (int j = 0; j < 4; ++j) {
                    const int tok = bm * 128 + wc * 64 + j * 16 + col;
                    const int b = tok >> 10, s = tok & 1023;
                    vtout[((size_t)((b << 4) + h) << 16) + ((size_t)d << 10) + s] =
                        f2bf(acc[i][j][r] + bias_v);
                }
            }
        }
    } else {
        #pragma unroll
        for (int j = 0; j < 4; ++j) {
            const int feat = bn * 128 + wc * 64 + j * 16 + col;
            const int h = feat >> 6, d = feat & 63;
            const float bias_v = bias[feat];
            #pragma unroll
            for (int i = 0; i < 4; ++i) {
                const int tok0 = bm * 128 + wr * 64 + i * 16 + rbase;
                #pragma unroll
                for (int r = 0; r < 4; ++r) {
                    const int tok = tok0 + r;
                    const int b = tok >> 10, s = tok & 1023;
                    const size_t off = ((size_t)((b << 4) + h) << 16) + ((size_t)s << 6) + d;
                    const float val = acc[i][j][r] + bias_v;
                    if (which == 0) qout[off] = f2bf(val);
                    else            kout[off] = f2bf(val);
                }
            }
        }
    }
}

// ---------------------------------------------------------------------------
// Kernel 2: flash attention, bf16 MFMA, fixed-offset softmax, S^T trick.
// 64-query blocks (grid 64 bh x 16 qt = 1024 blocks, ~34 KB LDS -> 4/CU).
// Wave owns 16 queries. S^T = K.Q^T so C-layout gives each thread 4
// CONSECUTIVE keys per reg group -> P written as packed ds_write_b64;
// l is a single per-thread register (q=ln), reduced once at the epilogue.
// PV: A=P (rows q=ln, contiguous), B=V^T (swizzled chunks). p=exp(fl(s/8 -
// (2-mask)*1e6)+1e6) reproduces the reference's 0.0625 quantization; l sums
// the bf16-rounded p so PV/l is exactly normalized.
// ---------------------------------------------------------------------------
__global__ __launch_bounds__(256) void attn_mfma(
    const unsigned short* __restrict__ Q, const unsigned short* __restrict__ K,
    const unsigned short* __restrict__ Vt, const float* __restrict__ mask,
    float* __restrict__ out)
{
    __shared__ unsigned short Qs[64 * 64];      // 8 KB, swizzled chunks
    __shared__ unsigned short Ks[64 * 64];      // 8 KB, swizzled
    __shared__ unsigned short Vts[64 * 64];     // 8 KB, swizzled  [d][key]
    __shared__ unsigned short Ps[4][16 * 72];   // 9 KB, per-wave [q][key]
    __shared__ float Ls[4][16];
    __shared__ float Ms[64];

    const int t    = threadIdx.x;
    const int lane = t & 63;
    const int w    = t >> 6;
    const int g    = lane >> 4;      // quad 0..3
    const int ln   = lane & 15;

    const int bh = blockIdx.x;       // x-major: all q-tiles of a bh on one XCD
    const int b  = bh >> 4;
    const int h  = bh & 15;
    const int q0 = blockIdx.y << 6;

    const unsigned short* __restrict__ qg = Q  + ((size_t)bh << 16);
    const unsigned short* __restrict__ kg = K  + ((size_t)bh << 16);
    const unsigned short* __restrict__ vg = Vt + ((size_t)bh << 16);

    // Stage Q tile (64 rows x 8 chunks of 16B), global-side XOR swizzle
    #pragma unroll
    for (int i = 0; i < 2; ++i) {
        const int G   = i * 256 + t;
        const int row = G >> 3;
        const int c   = (G & 7) ^ (row & 7);
        load_lds16(qg + (size_t)(q0 + row) * 64 + c * 8, (char*)Qs + i * 4096 + t * 16);
    }

    const f32x4 zero = {0.f, 0.f, 0.f, 0.f};
    f32x4 O[4];
    #pragma unroll
    for (int j = 0; j < 4; ++j) O[j] = zero;
    float lacc = 0.f;

    const int qrow = w * 16 + ln;    // this thread's query row for S^T / P

    for (int kt = 0; kt < 16; ++kt) {
        const int kt0 = kt << 6;
        __syncthreads();   // prev iter's Ks/Vts reads done
        #pragma unroll
        for (int i = 0; i < 2; ++i) {
            const int G   = i * 256 + t;
            const int row = G >> 3;
            const int c   = (G & 7) ^ (row & 7);
            load_lds16(kg + (size_t)(kt0 + row) * 64 + c * 8, (char*)Ks  + i * 4096 + t * 16);
            load_lds16(vg + (size_t)row * 1024 + kt0 + c * 8, (char*)Vts + i * 4096 + t * 16);
        }
        if (t < 64) Ms[t] = mask[(b << 10) + kt0 + t];
        __syncthreads();   // staged tiles visible

        // ---- S^T = K Q^T  (rows=64 keys, cols=wave's 16 queries) ----
        f32x4 sacc[4];
        #pragma unroll
        for (int j = 0; j < 4; ++j) sacc[j] = zero;
        #pragma unroll
        for (int ks = 0; ks < 2; ++ks) {
            bf16x8 qf = *(const bf16x8*)&Qs[qrow * 64 + (((ks * 4 + g) ^ (qrow & 7)) << 3)];
            bf16x8 kf[4];
            #pragma unroll
            for (int j = 0; j < 4; ++j) {
                const int krow = j * 16 + ln;
                kf[j] = *(const bf16x8*)&Ks[krow * 64 + (((ks * 4 + g) ^ (krow & 7)) << 3)];
            }
            #pragma unroll
            for (int j = 0; j < 4; ++j)
                sacc[j] = __builtin_amdgcn_mfma_f32_16x16x32_bf16(
                    kf[j], qf, sacc[j], 0, 0, 0);
        }

        // ---- softmax, fixed offset. Thread holds keys j*16+g*4+r, q=ln ----
        #pragma unroll
        for (int j = 0; j < 4; ++j) {
            unsigned short pb[4];
            #pragma unroll
            for (int r = 0; r < 4; ++r) {
                const int key = j * 16 + g * 4 + r;
                const float sv = sacc[j][r] * 0.125f - (2.0f - Ms[key]) * 1.0e6f;
                pb[r] = f2bf(__expf(sv + 1.0e6f));
                lacc += bf2f(pb[r]);
            }
            uint2 pk;
            pk.x = (unsigned int)pb[0] | ((unsigned int)pb[1] << 16);
            pk.y = (unsigned int)pb[2] | ((unsigned int)pb[3] << 16);
            *(uint2*)&Ps[w][ln * 72 + j * 16 + (g << 2)] = pk;   // 4 consecutive keys
        }
        // wave-local P RAW: drain LDS writes before fragment reads
        asm volatile("s_waitcnt lgkmcnt(0)" ::: "memory");

        // ---- O += P V  (A=P rows q=ln contiguous, B=V^T swizzled) ----
        #pragma unroll
        for (int ks = 0; ks < 2; ++ks) {
            bf16x8 pf = *(const bf16x8*)&Ps[w][ln * 72 + ks * 32 + (g << 3)];
            bf16x8 vf[4];
            #pragma unroll
            for (int j = 0; j < 4; ++j) {
                const int vrow = j * 16 + ln;
                vf[j] = *(const bf16x8*)&Vts[vrow * 64 + (((ks * 4 + g) ^ (vrow & 7)) << 3)];
            }
            #pragma unroll
            for (int j = 0; j < 4; ++j)
                O[j] = __builtin_amdgcn_mfma_f32_16x16x32_bf16(
                    pf, vf[j], O[j], 0, 0, 0);
        }
    }

    // Epilogue: l(q=ln) = reduce over quads; transpose via tiny LDS;
    // O C-layout: row q = g*4+r, col d = j*16+ln.
    float rs = lacc;
    rs += __shfl_xor(rs, 16);
    rs += __shfl_xor(rs, 32);
    if (lane < 16) Ls[w][ln] = rs;
    asm volatile("s_waitcnt lgkmcnt(0)" ::: "memory");
    #pragma unroll
    for (int r = 0; r < 4; ++r) {
        const float inv = 1.0f / Ls[w][(g << 2) + r];
        const int q = q0 + w * 16 + (g << 2) + r;
        const size_t base = (((size_t)(b << 10) + q) << 10) + (h << 6);
        #pragma unroll
        for (int j = 0; j < 4; ++j)
            out[base + j * 16 + ln] = O[j][r] * inv;
    }
}

// ---------------------------------------------------------------------------
extern "C" void kernel_launch(void* const* d_in, const int* in_sizes, int n_in,
                              void* d_out, int out_size, void* d_ws, size_t ws_size,
                              hipStream_t stream) {
    const float* hs   = (const float*)d_in[0];
    const float* mask = (const float*)d_in[1];
    const float* Wq   = (const float*)d_in[2];
    const float* bq   = (const float*)d_in[3];
    const float* Wk   = (const float*)d_in[4];
    const float* bk   = (const float*)d_in[5];
    const float* Wv   = (const float*)d_in[6];
    const float* bv   = (const float*)d_in[7];
    float* out = (float*)d_out;

    // Workspace: xb@0 (8MB) | wqb@8 wkb@10 wvb@12 (2MB each) |
    //            qb@14 (8MB) | kb@22 (8MB) | vtb@30 (8MB)  = 38 MB
    char* ws = (char*)d_ws;
    unsigned short* xb  = (unsigned short*)(ws);
    unsigned short* wqb = (unsigned short*)(ws + ((size_t)8  << 20));
    unsigned short* wkb = (unsigned short*)(ws + ((size_t)10 << 20));
    unsigned short* wvb = (unsigned short*)(ws + ((size_t)12 << 20));
    unsigned short* qb  = (unsigned short*)(ws + ((size_t)14 << 20));
    unsigned short* kb  = (unsigned short*)(ws + ((size_t)22 << 20));
    unsigned short* vtb = (unsigned short*)(ws + ((size_t)30 << 20));

    cvt_all<<<dim3(4096, 4), 256, 0, stream>>>(hs, Wq, Wk, Wv, xb, wqb, wkb, wvb);
    qkv_gemm_mfma<<<dim3(NTOK / 128, HID_ / 128, 3), 256, 0, stream>>>(
        xb, wqb, bq, wkb, bk, wvb, bv, qb, kb, vtb);
    attn_mfma<<<dim3(B_ * NH_, S_ / 64), 256, 0, stream>>>(qb, kb, vtb, mask, out);
}

// Round 6
// 162.683 us; speedup vs baseline: 1.0537x; 1.0537x over previous
//
#include <hip/hip_runtime.h>
#include <math.h>

// Problem constants
#define B_ 4
#define S_ 1024
#define HID_ 1024
#define NH_ 16
#define HD_ 64
#define NTOK (B_ * S_)           // 4096

typedef __attribute__((ext_vector_type(4))) float f32x4;
typedef __attribute__((ext_vector_type(8))) short bf16x8;   // 8 bf16 = 4 VGPRs

__device__ __forceinline__ unsigned short f2bf(float f) {
    union { float f; unsigned int u; } v; v.f = f;
    unsigned int r = v.u + 0x7fffu + ((v.u >> 16) & 1u);   // RNE
    return (unsigned short)(r >> 16);
}
__device__ __forceinline__ float bf2f(unsigned short u) {
    return __uint_as_float((unsigned int)u << 16);
}

// async global->LDS, 16 B per lane. LDS dest = wave-uniform base + lane*16.
__device__ __forceinline__ void load_lds16(const void* g, void* l) {
    __builtin_amdgcn_global_load_lds(
        (const __attribute__((address_space(1))) unsigned int*)(uintptr_t)g,
        (__attribute__((address_space(3))) unsigned int*)(uintptr_t)l,
        16, 0, 0);
}

// ---------------------------------------------------------------------------
// Kernel 0: f32 -> bf16 convert for x, Wq, Wk, Wv
// ---------------------------------------------------------------------------
__global__ __launch_bounds__(256) void cvt_all(
    const float* __restrict__ x, const float* __restrict__ wq,
    const float* __restrict__ wk, const float* __restrict__ wv,
    unsigned short* __restrict__ xb, unsigned short* __restrict__ wqb,
    unsigned short* __restrict__ wkb, unsigned short* __restrict__ wvb)
{
    const int which = blockIdx.y;
    const float* src = which == 0 ? x : which == 1 ? wq : which == 2 ? wk : wv;
    unsigned short* dst = which == 0 ? xb : which == 1 ? wqb : which == 2 ? wkb : wvb;
    const int n4 = (which == 0) ? (NTOK * HID_ / 4) : (HID_ * HID_ / 4);
    int i = blockIdx.x * 256 + threadIdx.x;
    if (i < n4) {
        float4 f = ((const float4*)src)[i];
        ushort4 o = make_ushort4(f2bf(f.x), f2bf(f.y), f2bf(f.z), f2bf(f.w));
        ((ushort4*)dst)[i] = o;
    }
}

// ---------------------------------------------------------------------------
// Kernel 1: QKV projection, bf16 MFMA. BK=64, XOR-swizzled LDS.
// Row = 128 B = 8 chunks of 16 B; LDS pos p of a row holds global chunk
// p^(row&7). Row stride = 32 dwords == 0 mod 32 banks, so fragment-read bank
// depends only on chunk position -> 2-way max (free). Staging itself is
// linear lane*16 (conflict-free, global_load_lds constraint); coalescing
// preserved (lanes permuted within the same 128 B rows).
// Q,K: A=x, B=W -> [B,NH,S,HD]. V: operands SWAPPED (A=W, B=x) so the
// [B,NH,HD,S] V^T write is lane-contiguous in s.
// ---------------------------------------------------------------------------
__global__ __launch_bounds__(256) void qkv_gemm_mfma(
    const unsigned short* __restrict__ xb,
    const unsigned short* __restrict__ Wqb, const float* __restrict__ bq,
    const unsigned short* __restrict__ Wkb, const float* __restrict__ bk,
    const unsigned short* __restrict__ Wvb, const float* __restrict__ bv,
    unsigned short* __restrict__ qout, unsigned short* __restrict__ kout,
    unsigned short* __restrict__ vtout)
{
    const int which = blockIdx.z;
    const unsigned short* __restrict__ W = which == 0 ? Wqb : which == 1 ? Wkb : Wvb;
    const float* __restrict__ bias       = which == 0 ? bq  : which == 1 ? bk  : bv;

    __shared__ unsigned short As[128 * 64];   // 16 KB, swizzled chunks
    __shared__ unsigned short Bs[128 * 64];   // 16 KB

    const int t    = threadIdx.x;
    const int lane = t & 63;
    const int w    = t >> 6;
    const int wr   = w >> 1;
    const int wc   = w & 1;
    const int g    = lane >> 4;       // quad 0..3
    const int lrow = lane & 15;

    const int bm = blockIdx.x;   // token tiles (32)
    const int bn = blockIdx.y;   // feature tiles (8)

    // Operand roles: which==2 swaps A<->B (m side = feats, n side = tokens)
    const unsigned short* __restrict__ Arow = (which == 2) ? W  : xb;
    const unsigned short* __restrict__ Brow = (which == 2) ? xb : W;
    const int am0 = (which == 2) ? bn * 128 : bm * 128;
    const int bn0 = (which == 2) ? bm * 128 : bn * 128;

    // staging: issue i covers rows i*32 + (t>>3); chunk c = (t&7)^((t>>3)&7)
    // (i*32 == 0 mod 8, so the swizzle term is issue-invariant)
    const int srow = t >> 3;                              // 0..31
    const int sc   = ((t & 7) ^ ((t >> 3) & 7)) << 3;     // short offset in row
    const unsigned short* gA = Arow + (size_t)(am0 + srow) * HID_ + sc;
    const unsigned short* gB = Brow + (size_t)(bn0 + srow) * HID_ + sc;

    const f32x4 zero = {0.f, 0.f, 0.f, 0.f};
    f32x4 acc[4][4];
    #pragma unroll
    for (int i = 0; i < 4; ++i)
        #pragma unroll
        for (int j = 0; j < 4; ++j) acc[i][j] = zero;

    for (int k0 = 0; k0 < HID_; k0 += 64) {
        __syncthreads();   // prev iter's ds_reads done before overwrite
        #pragma unroll
        for (int i = 0; i < 4; ++i) {
            load_lds16(gA + (size_t)(i * 32) * HID_ + k0, (char*)As + i * 4096 + t * 16);
            load_lds16(gB + (size_t)(i * 32) * HID_ + k0, (char*)Bs + i * 4096 + t * 16);
        }
        __syncthreads();   // staged data visible (drains vmcnt)

        #pragma unroll
        for (int ks = 0; ks < 2; ++ks) {
            bf16x8 af[4], bf[4];
            #pragma unroll
            for (int i = 0; i < 4; ++i) {
                const int row = wr * 64 + i * 16 + lrow;   // row&7 == lrow&7
                af[i] = *(const bf16x8*)&As[row * 64 + (((ks * 4 + g) ^ (row & 7)) << 3)];
            }
            #pragma unroll
            for (int j = 0; j < 4; ++j) {
                const int row = wc * 64 + j * 16 + lrow;
                bf[j] = *(const bf16x8*)&Bs[row * 64 + (((ks * 4 + g) ^ (row & 7)) << 3)];
            }
            #pragma unroll
            for (int i = 0; i < 4; ++i)
                #pragma unroll
                for (int j = 0; j < 4; ++j)
                    acc[i][j] = __builtin_amdgcn_mfma_f32_16x16x32_bf16(
                        af[i], bf[j], acc[i][j], 0, 0, 0);
        }
    }

    // Epilogue. D layout: col=lane&15 (n side), row=(lane>>4)*4+r (m side)
    const int col   = lane & 15;
    const int rbase = (lane >> 4) << 2;
    if (which == 2) {
        // m = feat, n = token. Consecutive lanes -> consecutive s. V^T write.
        #pragma unroll
        for (int i = 0; i < 4; ++i) {
            #pragma unroll
            for (int r = 0; r < 4; ++r) {
                const int feat = bn * 128 + wr * 64 + i * 16 + rbase + r;
                const int h = feat >> 6, d = feat & 63;
                const float bias_v = bias[feat];
                #pragma unroll
                for (int j = 0; j < 4; ++j) {
                    const int tok = bm * 128 + wc * 64 + j * 16 + col;
                    const int b = tok >> 10, s = tok & 1023;
                    vtout[((size_t)((b << 4) + h) << 16) + ((size_t)d << 10) + s] =
                        f2bf(acc[i][j][r] + bias_v);
                }
            }
        }
    } else {
        #pragma unroll
        for (int j = 0; j < 4; ++j) {
            const int feat = bn * 128 + wc * 64 + j * 16 + col;
            const int h = feat >> 6, d = feat & 63;
            const float bias_v = bias[feat];
            #pragma unroll
            for (int i = 0; i < 4; ++i) {
                const int tok0 = bm * 128 + wr * 64 + i * 16 + rbase;
                #pragma unroll
                for (int r = 0; r < 4; ++r) {
                    const int tok = tok0 + r;
                    const int b = tok >> 10, s = tok & 1023;
                    const size_t off = ((size_t)((b << 4) + h) << 16) + ((size_t)s << 6) + d;
                    const float val = acc[i][j][r] + bias_v;
                    if (which == 0) qout[off] = f2bf(val);
                    else            kout[off] = f2bf(val);
                }
            }
        }
    }
}

// ---------------------------------------------------------------------------
// Kernel 2: flash attention, bf16 MFMA, fixed-offset softmax, S^T trick.
// (unchanged from round 5)
// ---------------------------------------------------------------------------
__global__ __launch_bounds__(256) void attn_mfma(
    const unsigned short* __restrict__ Q, const unsigned short* __restrict__ K,
    const unsigned short* __restrict__ Vt, const float* __restrict__ mask,
    float* __restrict__ out)
{
    __shared__ unsigned short Qs[64 * 64];      // 8 KB, swizzled chunks
    __shared__ unsigned short Ks[64 * 64];      // 8 KB, swizzled
    __shared__ unsigned short Vts[64 * 64];     // 8 KB, swizzled  [d][key]
    __shared__ unsigned short Ps[4][16 * 72];   // 9 KB, per-wave [q][key]
    __shared__ float Ls[4][16];
    __shared__ float Ms[64];

    const int t    = threadIdx.x;
    const int lane = t & 63;
    const int w    = t >> 6;
    const int g    = lane >> 4;      // quad 0..3
    const int ln   = lane & 15;

    const int bh = blockIdx.x;       // x-major: all q-tiles of a bh on one XCD
    const int b  = bh >> 4;
    const int h  = bh & 15;
    const int q0 = blockIdx.y << 6;

    const unsigned short* __restrict__ qg = Q  + ((size_t)bh << 16);
    const unsigned short* __restrict__ kg = K  + ((size_t)bh << 16);
    const unsigned short* __restrict__ vg = Vt + ((size_t)bh << 16);

    // Stage Q tile (64 rows x 8 chunks of 16B), global-side XOR swizzle
    #pragma unroll
    for (int i = 0; i < 2; ++i) {
        const int G   = i * 256 + t;
        const int row = G >> 3;
        const int c   = (G & 7) ^ (row & 7);
        load_lds16(qg + (size_t)(q0 + row) * 64 + c * 8, (char*)Qs + i * 4096 + t * 16);
    }

    const f32x4 zero = {0.f, 0.f, 0.f, 0.f};
    f32x4 O[4];
    #pragma unroll
    for (int j = 0; j < 4; ++j) O[j] = zero;
    float lacc = 0.f;

    const int qrow = w * 16 + ln;    // this thread's query row for S^T / P

    for (int kt = 0; kt < 16; ++kt) {
        const int kt0 = kt << 6;
        __syncthreads();   // prev iter's Ks/Vts reads done
        #pragma unroll
        for (int i = 0; i < 2; ++i) {
            const int G   = i * 256 + t;
            const int row = G >> 3;
            const int c   = (G & 7) ^ (row & 7);
            load_lds16(kg + (size_t)(kt0 + row) * 64 + c * 8, (char*)Ks  + i * 4096 + t * 16);
            load_lds16(vg + (size_t)row * 1024 + kt0 + c * 8, (char*)Vts + i * 4096 + t * 16);
        }
        if (t < 64) Ms[t] = mask[(b << 10) + kt0 + t];
        __syncthreads();   // staged tiles visible

        // ---- S^T = K Q^T  (rows=64 keys, cols=wave's 16 queries) ----
        f32x4 sacc[4];
        #pragma unroll
        for (int j = 0; j < 4; ++j) sacc[j] = zero;
        #pragma unroll
        for (int ks = 0; ks < 2; ++ks) {
            bf16x8 qf = *(const bf16x8*)&Qs[qrow * 64 + (((ks * 4 + g) ^ (qrow & 7)) << 3)];
            bf16x8 kf[4];
            #pragma unroll
            for (int j = 0; j < 4; ++j) {
                const int krow = j * 16 + ln;
                kf[j] = *(const bf16x8*)&Ks[krow * 64 + (((ks * 4 + g) ^ (krow & 7)) << 3)];
            }
            #pragma unroll
            for (int j = 0; j < 4; ++j)
                sacc[j] = __builtin_amdgcn_mfma_f32_16x16x32_bf16(
                    kf[j], qf, sacc[j], 0, 0, 0);
        }

        // ---- softmax, fixed offset. Thread holds keys j*16+g*4+r, q=ln ----
        #pragma unroll
        for (int j = 0; j < 4; ++j) {
            unsigned short pb[4];
            #pragma unroll
            for (int r = 0; r < 4; ++r) {
                const int key = j * 16 + g * 4 + r;
                const float sv = sacc[j][r] * 0.125f - (2.0f - Ms[key]) * 1.0e6f;
                pb[r] = f2bf(__expf(sv + 1.0e6f));
                lacc += bf2f(pb[r]);
            }
            uint2 pk;
            pk.x = (unsigned int)pb[0] | ((unsigned int)pb[1] << 16);
            pk.y = (unsigned int)pb[2] | ((unsigned int)pb[3] << 16);
            *(uint2*)&Ps[w][ln * 72 + j * 16 + (g << 2)] = pk;   // 4 consecutive keys
        }
        // wave-local P RAW: drain LDS writes before fragment reads
        asm volatile("s_waitcnt lgkmcnt(0)" ::: "memory");

        // ---- O += P V  (A=P rows q=ln contiguous, B=V^T swizzled) ----
        #pragma unroll
        for (int ks = 0; ks < 2; ++ks) {
            bf16x8 pf = *(const bf16x8*)&Ps[w][ln * 72 + ks * 32 + (g << 3)];
            bf16x8 vf[4];
            #pragma unroll
            for (int j = 0; j < 4; ++j) {
                const int vrow = j * 16 + ln;
                vf[j] = *(const bf16x8*)&Vts[vrow * 64 + (((ks * 4 + g) ^ (vrow & 7)) << 3)];
            }
            #pragma unroll
            for (int j = 0; j < 4; ++j)
                O[j] = __builtin_amdgcn_mfma_f32_16x16x32_bf16(
                    pf, vf[j], O[j], 0, 0, 0);
        }
    }

    // Epilogue: l(q=ln) = reduce over quads; transpose via tiny LDS;
    // O C-layout: row q = g*4+r, col d = j*16+ln.
    float rs = lacc;
    rs += __shfl_xor(rs, 16);
    rs += __shfl_xor(rs, 32);
    if (lane < 16) Ls[w][ln] = rs;
    asm volatile("s_waitcnt lgkmcnt(0)" ::: "memory");
    #pragma unroll
    for (int r = 0; r < 4; ++r) {
        const float inv = 1.0f / Ls[w][(g << 2) + r];
        const int q = q0 + w * 16 + (g << 2) + r;
        const size_t base = (((size_t)(b << 10) + q) << 10) + (h << 6);
        #pragma unroll
        for (int j = 0; j < 4; ++j)
            out[base + j * 16 + ln] = O[j][r] * inv;
    }
}

// ---------------------------------------------------------------------------
extern "C" void kernel_launch(void* const* d_in, const int* in_sizes, int n_in,
                              void* d_out, int out_size, void* d_ws, size_t ws_size,
                              hipStream_t stream) {
    const float* hs   = (const float*)d_in[0];
    const float* mask = (const float*)d_in[1];
    const float* Wq   = (const float*)d_in[2];
    const float* bq   = (const float*)d_in[3];
    const float* Wk   = (const float*)d_in[4];
    const float* bk   = (const float*)d_in[5];
    const float* Wv   = (const float*)d_in[6];
    const float* bv   = (const float*)d_in[7];
    float* out = (float*)d_out;

    // Workspace: xb@0 (8MB) | wqb@8 wkb@10 wvb@12 (2MB each) |
    //            qb@14 (8MB) | kb@22 (8MB) | vtb@30 (8MB)  = 38 MB
    char* ws = (char*)d_ws;
    unsigned short* xb  = (unsigned short*)(ws);
    unsigned short* wqb = (unsigned short*)(ws + ((size_t)8  << 20));
    unsigned short* wkb = (unsigned short*)(ws + ((size_t)10 << 20));
    unsigned short* wvb = (unsigned short*)(ws + ((size_t)12 << 20));
    unsigned short* qb  = (unsigned short*)(ws + ((size_t)14 << 20));
    unsigned short* kb  = (unsigned short*)(ws + ((size_t)22 << 20));
    unsigned short* vtb = (unsigned short*)(ws + ((size_t)30 << 20));

    cvt_all<<<dim3(4096, 4), 256, 0, stream>>>(hs, Wq, Wk, Wv, xb, wqb, wkb, wvb);
    qkv_gemm_mfma<<<dim3(NTOK / 128, HID_ / 128, 3), 256, 0, stream>>>(
        xb, wqb, bq, wkb, bk, wvb, bv, qb, kb, vtb);
    attn_mfma<<<dim3(B_ * NH_, S_ / 64), 256, 0, stream>>>(qb, kb, vtb, mask, out);
}